// Round 1
// baseline (249.964 us; speedup 1.0000x reference)
//
#include <hip/hip_runtime.h>
#include <math.h>

#define D 4096

// In-register FWHT over the 6 bits of the register index (64 values/thread).
__device__ __forceinline__ void fwht64(float* v) {
#pragma unroll
    for (int h = 1; h < 64; h <<= 1) {
#pragma unroll
        for (int i = 0; i < 64; i += 2 * h) {
#pragma unroll
            for (int j = i; j < i + h; ++j) {
                const float a = v[j];
                const float b = v[j + h];
                v[j]     = a + b;
                v[j + h] = a - b;
            }
        }
    }
}

// Precompute g = g_mu + softplus(g_rho)*eps, pre-permuted into layout-B order:
// gq[l*64 + k] = g[e(k,l)], e = (l&3) | (k<<2) | ((l>>2)<<8)
__global__ void whvi_prep(const float* __restrict__ g_mu,
                          const float* __restrict__ g_rho,
                          const float* __restrict__ eps,
                          float* __restrict__ gq) {
    const int i = blockIdx.x * 64 + threadIdx.x;   // i = l*64 + k
    const int l = i >> 6, k = i & 63;
    const int e = (l & 3) | (k << 2) | ((l >> 2) << 8);
    const float r  = g_rho[e];
    const float sp = (r > 20.f) ? r : log1pf(expf(r));   // stable softplus
    gq[i] = g_mu[e] + sp * eps[e];
}

// One wave (64 lanes) per row. Layout A: lane l, reg r holds element
// e = (r&3) | (l<<2) | ((r>>2)<<8)   -> register bits {0,1,8,9,10,11}
// Layout B: lane l, reg k holds element
// e = (l&3) | (k<<2) | ((l>>2)<<8)   -> register bits {2..7}
// FWHT butterfly stages commute per-bit, so: regFWHT(A) -> transpose ->
// regFWHT(B) covers all 12 bits. LDS xor-swizzle sigma(e)=e^((e>>6)&0x1C)
// keeps b128 writes minimal-phase and b32 reads at <=2-way (free).
__global__ void __launch_bounds__(64) whvi_main(
    const float* __restrict__ x,  const float* __restrict__ s1,
    const float* __restrict__ s2, const float* __restrict__ gq,
    const float* __restrict__ g_mu, const float* __restrict__ g_rho,
    const float* __restrict__ eps, float* __restrict__ out) {
    __shared__ alignas(16) float lds[D];   // 16 KiB -> 10 waves/CU
    const int l = threadIdx.x;
    const long long row = blockIdx.x;
    const float* xr = x + row * (long long)D;
    float v[64];

    // ---- load x*s2, layout A (coalesced dwordx4) ----
#pragma unroll
    for (int q = 0; q < 16; ++q) {
        const int base = (l << 2) + (q << 8);
        const float4 xv = *reinterpret_cast<const float4*>(xr + base);
        const float4 sv = *reinterpret_cast<const float4*>(s2 + base);
        v[4 * q + 0] = xv.x * sv.x;
        v[4 * q + 1] = xv.y * sv.y;
        v[4 * q + 2] = xv.z * sv.z;
        v[4 * q + 3] = xv.w * sv.w;
    }

    fwht64(v);                       // FWHT-1a: e-bits {0,1,8,9,10,11}

    // ---- transpose 1: write layout A (b128), read layout B (b32) ----
#pragma unroll
    for (int q = 0; q < 16; ++q) {
        const int addr = ((l ^ (q & 7)) << 2) + (q << 8);   // swizzled
        *reinterpret_cast<float4*>(&lds[addr]) =
            make_float4(v[4 * q], v[4 * q + 1], v[4 * q + 2], v[4 * q + 3]);
    }
    __syncthreads();
    {
        const int xb = (l & 3) | ((l >> 2) << 8);
        const int mk = (l >> 2) & 7;                        // swizzle mask
#pragma unroll
        for (int k = 0; k < 64; ++k)
            v[k] = lds[xb + ((k ^ mk) << 2)];
    }

    fwht64(v);                       // FWHT-1b: e-bits {2..7}  (FWHT #1 done)

    // ---- multiply by g (pre-permuted, L1-resident) ----
    if (gq) {
#pragma unroll
        for (int m = 0; m < 16; ++m) {
            const float4 gv = *reinterpret_cast<const float4*>(gq + l * 64 + 4 * m);
            v[4 * m + 0] *= gv.x;
            v[4 * m + 1] *= gv.y;
            v[4 * m + 2] *= gv.z;
            v[4 * m + 3] *= gv.w;
        }
    } else {  // fallback if d_ws too small: compute softplus inline
#pragma unroll
        for (int k = 0; k < 64; ++k) {
            const int e = (l & 3) | (k << 2) | ((l >> 2) << 8);
            const float r  = g_rho[e];
            const float sp = (r > 20.f) ? r : log1pf(expf(r));
            v[k] *= g_mu[e] + sp * eps[e];
        }
    }

    fwht64(v);                       // FWHT-2a: e-bits {2..7}

    // ---- transpose 2: write layout B (b32), read layout A (b128) ----
    __syncthreads();                 // protect WAR on lds
    {
        const int xb = (l & 3) | ((l >> 2) << 8);
        const int mk = (l >> 2) & 7;
#pragma unroll
        for (int k = 0; k < 64; ++k)
            lds[xb + ((k ^ mk) << 2)] = v[k];
    }
    __syncthreads();
#pragma unroll
    for (int q = 0; q < 16; ++q) {
        const int addr = ((l ^ (q & 7)) << 2) + (q << 8);
        const float4 t = *reinterpret_cast<const float4*>(&lds[addr]);
        v[4 * q + 0] = t.x;
        v[4 * q + 1] = t.y;
        v[4 * q + 2] = t.z;
        v[4 * q + 3] = t.w;
    }

    fwht64(v);                       // FWHT-2b: e-bits {0,1,8,9,10,11}

    // ---- multiply by s1, store (coalesced dwordx4) ----
    float* outr = out + row * (long long)D;
#pragma unroll
    for (int q = 0; q < 16; ++q) {
        const int base = (l << 2) + (q << 8);
        const float4 sv = *reinterpret_cast<const float4*>(s1 + base);
        float4 o;
        o.x = v[4 * q + 0] * sv.x;
        o.y = v[4 * q + 1] * sv.y;
        o.z = v[4 * q + 2] * sv.z;
        o.w = v[4 * q + 3] * sv.w;
        *reinterpret_cast<float4*>(outr + base) = o;
    }
}

extern "C" void kernel_launch(void* const* d_in, const int* in_sizes, int n_in,
                              void* d_out, int out_size, void* d_ws, size_t ws_size,
                              hipStream_t stream) {
    const float* x     = (const float*)d_in[0];
    const float* s1    = (const float*)d_in[1];
    const float* s2    = (const float*)d_in[2];
    const float* g_mu  = (const float*)d_in[3];
    const float* g_rho = (const float*)d_in[4];
    const float* eps   = (const float*)d_in[5];
    float* out = (float*)d_out;
    const int rows = in_sizes[0] / D;

    float* gq = nullptr;
    if (ws_size >= (size_t)D * sizeof(float)) {
        gq = (float*)d_ws;
        whvi_prep<<<D / 64, 64, 0, stream>>>(g_mu, g_rho, eps, gq);
    }
    whvi_main<<<rows, 64, 0, stream>>>(x, s1, s2, gq, g_mu, g_rho, eps, out);
}